// Round 8
// baseline (458.878 us; speedup 1.0000x reference)
//
#include <hip/hip_runtime.h>
#include <math.h>

// Problem constants (fixed by setup_inputs)
#define B_  32
#define N_  1024
#define D_  64
#define H_  8
#define K_  128
#define HK_ 1024

#define GLB(p) ((const __attribute__((address_space(1))) void*)(p))
#define LDSP(p) ((__attribute__((address_space(3))) void*)(p))

// ---------------------------------------------------------------------------
// K1: x[b,n,d] = mean_t node_set[b,d,n,t]; inv_xn[b,n] = 1/||x[b,n,:]||;
// part1[(b*16+tile)*64+d] = sum_{n in tile} x[b,n,d]  (pure stores, no atomics)
// ---------------------------------------------------------------------------
__global__ __launch_bounds__(512) void k1_mean(const float* __restrict__ ns,
        float* __restrict__ x, float* __restrict__ invxn,
        float* __restrict__ part1) {
    __shared__ float tile[64][65];
    int b    = blockIdx.x >> 4;
    int n0   = (blockIdx.x & 15) << 6;
    int lane = threadIdx.x & 63;
    int w    = threadIdx.x >> 6;            // 0..7
    #pragma unroll
    for (int j = 0; j < 8; ++j) {
        int d = w * 8 + j;
        const float4* p = (const float4*)(ns +
            ((size_t)((b * 64 + d) * 1024 + n0 + lane)) * 12);   // 48B aligned
        float4 a = p[0], c = p[1], e = p[2];
        float s = ((a.x + a.y) + (a.z + a.w)) + ((c.x + c.y) + (c.z + c.w))
                + ((e.x + e.y) + (e.z + e.w));
        tile[lane][d] = s * (1.0f / 12.0f);
    }
    __syncthreads();
    #pragma unroll
    for (int j = 0; j < 8; ++j) {
        int r = w * 8 + j;
        float v = tile[r][lane];
        x[((size_t)(b * 1024 + n0 + r)) * 64 + lane] = v;
        float ss = v * v;
        #pragma unroll
        for (int o = 32; o; o >>= 1) ss += __shfl_xor(ss, o);
        if (lane == 0) invxn[b * 1024 + n0 + r] = 1.0f / sqrtf(fmaxf(ss, 1e-30f));
    }
    if (threadIdx.x < 64) {
        float s = 0.0f;
        #pragma unroll 16
        for (int r = 0; r < 64; ++r) s += tile[r][threadIdx.x];
        part1[(size_t)blockIdx.x * 64 + threadIdx.x] = s;   // blockIdx = b*16+tile
    }
}

// ---------------------------------------------------------------------------
// K3: deterministic. Per block (b, 128-n slice): reduce part1 (fixed order) ->
// temp, h_avg = tanh(temp@W0), att[n] = x.h_avg, cent partial for slice ->
// part2[(b*8+slice)*64+d]. grid = B*8 = 256 blocks, block 256.
// ---------------------------------------------------------------------------
__global__ __launch_bounds__(256) void k3_cent(const float* __restrict__ x,
        const float* __restrict__ part1, const float* __restrict__ W0,
        float* __restrict__ part2) {
    __shared__ float t[64];
    __shared__ float ha[64];
    __shared__ float cp[4][64];
    int b    = blockIdx.x >> 3;
    int n0   = (blockIdx.x & 7) << 7;
    int lane = threadIdx.x & 63;
    int w    = threadIdx.x >> 6;
    if (threadIdx.x < 64) {
        float s = 0.0f;
        #pragma unroll
        for (int j = 0; j < 16; ++j) s += part1[(size_t)(b * 16 + j) * 64 + threadIdx.x];
        t[threadIdx.x] = s * (1.0f / 1024.0f);
    }
    __syncthreads();
    if (threadIdx.x < 64) {                  // h_avg: 64x64 matvec
        float a = 0.0f;
        #pragma unroll 8
        for (int d = 0; d < 64; ++d) a += t[d] * W0[d * 64 + threadIdx.x];
        ha[threadIdx.x] = tanhf(a);
    }
    __syncthreads();
    float hv = ha[lane];
    float cw = 0.0f;
    for (int nn = w; nn < 128; nn += 4) {    // fixed per-wave order
        float xv = x[((size_t)(b * 1024 + n0 + nn)) * 64 + lane];
        float d  = xv * hv;
        #pragma unroll
        for (int o = 32; o; o >>= 1) d += __shfl_xor(d, o);   // att broadcast
        cw += d * xv;
    }
    cp[w][lane] = cw;
    __syncthreads();
    if (w == 0)
        part2[(size_t)blockIdx.x * 64 + lane] =
            ((cp[0][lane] + cp[1][lane]) + (cp[2][lane] + cp[3][lane]));
}

// ---------------------------------------------------------------------------
// K4: reconstruct cent from 8 slice partials (fixed order), then centroid MLP
// -> bc, invcn. One wave per 4 hk. grid = 2048, block 256.
// ---------------------------------------------------------------------------
__global__ __launch_bounds__(256) void k4_bc(const float* __restrict__ part2,
        const float* __restrict__ w_i2c, const float* __restrict__ b_i2c,
        const float* __restrict__ W_lin, const float* __restrict__ b_lin,
        float* __restrict__ bc, float* __restrict__ invcn) {
    int lane = threadIdx.x & 63;
    int w    = threadIdx.x >> 6;
    int gg   = blockIdx.x * 4 + w;
    int b    = gg >> 8;
    int kk0  = (gg & 255) * 4;
    float c = 0.0f;
    #pragma unroll
    for (int s = 0; s < 8; ++s) c += part2[(size_t)(b * 8 + s) * 64 + lane];
    float b1[8];
    #pragma unroll
    for (int h = 0; h < 8; ++h) b1[h] = fmaxf(c * w_i2c[h] + b_i2c[h], 0.0f);
    #pragma unroll
    for (int u = 0; u < 4; ++u) {
        int kk = kk0 + u;
        float pre = b_lin[kk];
        #pragma unroll
        for (int h = 0; h < 8; ++h) pre += b1[h] * W_lin[kk * 8 + h];
        float v = fmaxf(pre, 0.0f);
        bc[((size_t)(b * 1024 + kk)) * 64 + lane] = v;
        float ss = v * v;
        #pragma unroll
        for (int o = 32; o; o >>= 1) ss += __shfl_xor(ss, o);
        if (lane == 0) invcn[b * 1024 + kk] = (ss > 0.0f) ? (1.0f / sqrtf(ss)) : 0.0f;
    }
}

// ---------------------------------------------------------------------------
// K5 (dominant, fp32 VALU GEMM): per (b, 128-n tile), loop 8 heads.
// v4: single bct buffer (71KB LDS -> 2 blocks/CU, 2 waves/SIMD latency
// hiding), explicit fmaf chains (cut the ~2x VALU-issue tax), XCD-co-located
// b (all 8 n-tiles of b on one XCD -> bc/x L2-resident). 8x8 register tile,
// global_load_lds staging with XOR-swizzled source. grid 256, block 256.
// ---------------------------------------------------------------------------
__global__ __launch_bounds__(256, 2) void k5_assign(const float* __restrict__ x,
        const float* __restrict__ bc, const float* __restrict__ invxn,
        const float* __restrict__ invcn, const float* __restrict__ conv_w,
        const float* __restrict__ conv_b, float* __restrict__ C) {
    __shared__ float xt[128][68];        // padded, staged once      (34.8 KB)
    __shared__ float bct[128 * 64];      // unpadded, swizzled       (32 KB)
    __shared__ float invx_s[128];
    __shared__ float invc_s[2][128];
    __shared__ float sredW[128][4];      // [col][wave] partials     (2 KB)
    int b   = blockIdx.x & 31;           // XCD co-location: same-b blocks
    int n0  = (blockIdx.x >> 5) << 7;    // are == mod 8 -> same XCD L2
    int tid = threadIdx.x;
    int l   = tid & 63, w = tid >> 6;
    int q   = tid >> 4, p = tid & 15;    // k-slot (16), n-slot (16)
    int rxor = q & 7;                    // read-side swizzle key
    int rl  = l >> 4, cl = l & 15;       // staging lane coords
    {   // stage x tile: 128 rows x 64 d (one-time)
        int r = tid >> 1, dh = (tid & 1) << 5;
        const float4* src = (const float4*)(x + ((size_t)(b * 1024 + n0 + r)) * 64 + dh);
        float4* dst = (float4*)(&xt[r][dh]);
        #pragma unroll
        for (int u = 0; u < 8; ++u) dst[u] = src[u];
    }
    if (tid < 128) {
        invx_s[tid]    = invxn[b * 1024 + n0 + tid];
        invc_s[0][tid] = invcn[b * 1024 + tid];
    }
    {   // async stage head-0 bc tile, swizzled source: slot c holds logical c^(r&7)
        const float* hb = bc + ((size_t)(b * 1024)) * 64;
        #pragma unroll
        for (int t = 0; t < 8; ++t) {
            int chunk = w * 8 + t;
            int r = chunk * 4 + rl;
            const float* src = hb + (size_t)r * 64 + ((cl ^ (r & 7)) << 2);
            __builtin_amdgcn_global_load_lds(GLB(src), LDSP(&bct[chunk * 256]), 16, 0, 0);
        }
    }
    float Cacc[8][8];
    #pragma unroll
    for (int i = 0; i < 8; ++i)
        #pragma unroll
        for (int j = 0; j < 8; ++j) Cacc[i][j] = 0.0f;
    float cb = conv_b[0];

    for (int h = 0; h < 8; ++h) {
        int cur = h & 1, nxt = cur ^ 1;
        __syncthreads();                 // A(h): drains vmcnt -> bct[h] ready
        // GEMM: acc[i][j] = bc_row(q+16i) . x_row(p+16j), fmaf chains,
        // software-pipelined with named A/B register sets
        const float4* B4 = (const float4*)(&bct[0]);
        float acc[8][8];
        #pragma unroll
        for (int i = 0; i < 8; ++i)
            #pragma unroll
            for (int j = 0; j < 8; ++j) acc[i][j] = 0.0f;
        float4 bvA[8], xvA[8], bvB[8], xvB[8];
        #pragma unroll
        for (int i = 0; i < 8; ++i) bvA[i] = B4[(q + 16 * i) * 16 + (0 ^ rxor)];
        #pragma unroll
        for (int j = 0; j < 8; ++j) xvA[j] = *(const float4*)(&xt[p + 16 * j][0]);
        #pragma unroll 1
        for (int c = 0; c < 16; c += 2) {
            #pragma unroll
            for (int i = 0; i < 8; ++i) bvB[i] = B4[(q + 16 * i) * 16 + ((c + 1) ^ rxor)];
            #pragma unroll
            for (int j = 0; j < 8; ++j) xvB[j] = *(const float4*)(&xt[p + 16 * j][(c + 1) << 2]);
            #pragma unroll
            for (int i = 0; i < 8; ++i)
                #pragma unroll
                for (int j = 0; j < 8; ++j)
                    acc[i][j] = fmaf(bvA[i].w, xvA[j].w,
                                fmaf(bvA[i].z, xvA[j].z,
                                fmaf(bvA[i].y, xvA[j].y,
                                fmaf(bvA[i].x, xvA[j].x, acc[i][j]))));
            if (c + 2 < 16) {
                #pragma unroll
                for (int i = 0; i < 8; ++i) bvA[i] = B4[(q + 16 * i) * 16 + ((c + 2) ^ rxor)];
                #pragma unroll
                for (int j = 0; j < 8; ++j) xvA[j] = *(const float4*)(&xt[p + 16 * j][(c + 2) << 2]);
            }
            #pragma unroll
            for (int i = 0; i < 8; ++i)
                #pragma unroll
                for (int j = 0; j < 8; ++j)
                    acc[i][j] = fmaf(bvB[i].w, xvB[j].w,
                                fmaf(bvB[i].z, xvB[j].z,
                                fmaf(bvB[i].y, xvB[j].y,
                                fmaf(bvB[i].x, xvB[j].x, acc[i][j]))));
        }
        // fold cosine denominators; per-thread k-partials of the normalizer
        float part[8];
        #pragma unroll
        for (int j = 0; j < 8; ++j) part[j] = 0.0f;
        #pragma unroll
        for (int i = 0; i < 8; ++i) {
            float ic = invc_s[cur][q + 16 * i];
            #pragma unroll
            for (int j = 0; j < 8; ++j) {
                float v = acc[i][j] * ic * invx_s[p + 16 * j];
                acc[i][j] = v;
                part[j] += v;
            }
        }
        // wave-level reduce over the 4 q'-lane-groups (fixed order)
        #pragma unroll
        for (int j = 0; j < 8; ++j) {
            part[j] += __shfl_xor(part[j], 16);
            part[j] += __shfl_xor(part[j], 32);
        }
        if (l < 16) {
            #pragma unroll
            for (int j = 0; j < 8; ++j) sredW[p + 16 * j][w] = part[j];
        }
        __syncthreads();                 // B(h): sredW ready; bct reads done
        if (h < 7) {   // stage next head into the (now-free) bct buffer
            const float* hb = bc + ((size_t)(b * 1024 + (h + 1) * 128)) * 64;
            #pragma unroll
            for (int t = 0; t < 8; ++t) {
                int chunk = w * 8 + t;
                int r = chunk * 4 + rl;
                const float* src = hb + (size_t)r * 64 + ((cl ^ (r & 7)) << 2);
                __builtin_amdgcn_global_load_lds(GLB(src), LDSP(&bct[chunk * 256]), 16, 0, 0);
            }
            if (tid < 128) invc_s[nxt][tid] = invcn[b * 1024 + (h + 1) * 128 + tid];
        }
        // Cacc update overlaps the staging loads
        float cwv = conv_w[h];
        #pragma unroll
        for (int j = 0; j < 8; ++j) {
            float4 sv = *(const float4*)(&sredW[p + 16 * j][0]);
            float s  = (sv.x + sv.y) + (sv.z + sv.w);
            float si = 1.0f / (s + 1e-10f);
            #pragma unroll
            for (int i = 0; i < 8; ++i) Cacc[i][j] = fmaf(cwv * si, acc[i][j], Cacc[i][j]);
        }
    }
    #pragma unroll
    for (int i = 0; i < 8; ++i) {
        int k = q + 16 * i;
        #pragma unroll
        for (int j = 0; j < 8; ++j)
            C[((size_t)(b * 128 + k)) * 1024 + n0 + p + 16 * j] = Cacc[i][j] + cb;
    }
}

// ---------------------------------------------------------------------------
// K6: LDS-tiled GEMM nns[k,d] = sum_n C[b,k,n]*x[b,n,d], fused projection.
// XCD-co-located b; float4 ct reads + fmaf.
// ---------------------------------------------------------------------------
__global__ __launch_bounds__(256, 2) void k6_out(const float* __restrict__ C,
        const float* __restrict__ x, const float* __restrict__ Wf,
        const float* __restrict__ bfeat, float* __restrict__ out) {
    __shared__ float xt[128][68];
    __shared__ float ct[16][132];
    __shared__ float nnst[16][68];
    __shared__ float wfs[64][68];
    int b   = blockIdx.x & 31;           // same-b blocks -> same XCD
    int k0  = (blockIdx.x >> 5) << 4;
    int tid = threadIdx.x;
    int kq  = tid >> 4, p = tid & 15;
    for (int t = tid; t < 4096; t += 256) wfs[t >> 6][t & 63] = Wf[t];
    float a0 = 0.0f, a1 = 0.0f, a2 = 0.0f, a3 = 0.0f;
    for (int c = 0; c < 8; ++c) {
        __syncthreads();
        {
            int r = tid >> 1, dh = (tid & 1) << 5;
            const float4* src = (const float4*)(x + ((size_t)(b * 1024 + c * 128 + r)) * 64 + dh);
            float4* dst = (float4*)(&xt[r][dh]);
            #pragma unroll
            for (int u = 0; u < 8; ++u) dst[u] = src[u];
        }
        for (int t = tid; t < 2048; t += 256)
            ct[t >> 7][t & 127] = C[((size_t)(b * 128 + k0 + (t >> 7))) * 1024 + c * 128 + (t & 127)];
        __syncthreads();
        #pragma unroll 4
        for (int n = 0; n < 128; n += 4) {
            float4 cv = *(const float4*)(&ct[kq][n]);
            float4 x0 = *(const float4*)(&xt[n + 0][p << 2]);
            float4 x1 = *(const float4*)(&xt[n + 1][p << 2]);
            float4 x2 = *(const float4*)(&xt[n + 2][p << 2]);
            float4 x3 = *(const float4*)(&xt[n + 3][p << 2]);
            a0 = fmaf(cv.w, x3.x, fmaf(cv.z, x2.x, fmaf(cv.y, x1.x, fmaf(cv.x, x0.x, a0))));
            a1 = fmaf(cv.w, x3.y, fmaf(cv.z, x2.y, fmaf(cv.y, x1.y, fmaf(cv.x, x0.y, a1))));
            a2 = fmaf(cv.w, x3.z, fmaf(cv.z, x2.z, fmaf(cv.y, x1.z, fmaf(cv.x, x0.z, a2))));
            a3 = fmaf(cv.w, x3.w, fmaf(cv.z, x2.w, fmaf(cv.y, x1.w, fmaf(cv.x, x0.w, a3))));
        }
    }
    __syncthreads();
    nnst[kq][(p << 2) + 0] = a0;
    nnst[kq][(p << 2) + 1] = a1;
    nnst[kq][(p << 2) + 2] = a2;
    nnst[kq][(p << 2) + 3] = a3;
    __syncthreads();
    float o0 = bfeat[(p << 2) + 0], o1 = bfeat[(p << 2) + 1];
    float o2 = bfeat[(p << 2) + 2], o3 = bfeat[(p << 2) + 3];
    #pragma unroll
    for (int dc = 0; dc < 64; dc += 4) {
        float4 nv = *(const float4*)(&nnst[kq][dc]);
        float4 w0 = *(const float4*)(&wfs[(p << 2) + 0][dc]);
        float4 w1 = *(const float4*)(&wfs[(p << 2) + 1][dc]);
        float4 w2 = *(const float4*)(&wfs[(p << 2) + 2][dc]);
        float4 w3 = *(const float4*)(&wfs[(p << 2) + 3][dc]);
        o0 = fmaf(nv.w, w0.w, fmaf(nv.z, w0.z, fmaf(nv.y, w0.y, fmaf(nv.x, w0.x, o0))));
        o1 = fmaf(nv.w, w1.w, fmaf(nv.z, w1.z, fmaf(nv.y, w1.y, fmaf(nv.x, w1.x, o1))));
        o2 = fmaf(nv.w, w2.w, fmaf(nv.z, w2.z, fmaf(nv.y, w2.y, fmaf(nv.x, w2.x, o2))));
        o3 = fmaf(nv.w, w3.w, fmaf(nv.z, w3.z, fmaf(nv.y, w3.y, fmaf(nv.x, w3.x, o3))));
    }
    float4 ov = make_float4(o0, o1, o2, o3);
    *(float4*)(out + ((size_t)(b * 128 + k0 + kq)) * 64 + (p << 2)) = ov;
}

// ---------------------------------------------------------------------------
extern "C" void kernel_launch(void* const* d_in, const int* in_sizes, int n_in,
                              void* d_out, int out_size, void* d_ws, size_t ws_size,
                              hipStream_t stream) {
    const float* node_set = (const float*)d_in[0];
    // d_in[1] = adj : UNUSED by the reference
    const float* W0     = (const float*)d_in[2];
    const float* w_i2c  = (const float*)d_in[3];
    const float* b_i2c  = (const float*)d_in[4];
    const float* W_lin  = (const float*)d_in[5];
    const float* b_lin  = (const float*)d_in[6];
    const float* conv_w = (const float*)d_in[7];
    const float* conv_b = (const float*)d_in[8];
    const float* W_feat = (const float*)d_in[9];
    const float* b_feat = (const float*)d_in[10];
    float* out = (float*)d_out;
    float* ws  = (float*)d_ws;

    // workspace layout (floats) — every array fully overwritten each call
    float* x     = ws;                      // 2,097,152  [B,N,D]
    float* invxn = ws + 2097152;            //    32,768  [B,N]
    float* part1 = ws + 2129920;            //    32,768  [B,16,64]
    float* bc    = ws + 2162688;            // 2,097,152  [B,HK,D]
    float* invcn = ws + 4259840;            //    32,768  [B,HK]
    float* Cmat  = ws + 4292608;            // 4,194,304  [B,K,N]
    float* part2 = Cmat;                    //    16,384  [B,8,64] (dead before k5)

    k1_mean  <<<B_ * 16, 512, 0, stream>>>(node_set, x, invxn, part1);
    k3_cent  <<<B_ * 8,  256, 0, stream>>>(x, part1, W0, part2);
    k4_bc    <<<2048,    256, 0, stream>>>(part2, w_i2c, b_i2c, W_lin, b_lin, bc, invcn);
    k5_assign<<<B_ * 8,  256, 0, stream>>>(x, bc, invxn, invcn, conv_w, conv_b, Cmat);
    k6_out   <<<B_ * 8,  256, 0, stream>>>(Cmat, x, W_feat, b_feat, out);
}